// Round 2
// baseline (749.027 us; speedup 1.0000x reference)
//
#include <hip/hip_runtime.h>
#include <hip/hip_bf16.h>

// Problem constants
#define B_   256
#define P_   192
#define DV_  768
#define DT_  768
#define E_   256
#define A_   8
#define K_   4

// ---------------------------------------------------------------------------
// GEMM: C[M x 256] = A[M x 768] @ W[768 x 256] + bias
// MODE 0: plain rows (stride 768)         -- textual, attribute
// MODE 1: visual token-0 rows (stride 193*768)
// MODE 2: patch rows: r -> vf[r/192, 1 + r%192, :]
// Tile: BM=128, BN=64, BK=16, 256 threads, 8x4 per thread.
// ---------------------------------------------------------------------------
template <int MODE>
__device__ __forceinline__ const float* row_ptr(const float* A, int r) {
  if constexpr (MODE == 0) {
    return A + (size_t)r * 768;
  } else if constexpr (MODE == 1) {
    return A + (size_t)r * (193 * 768);
  } else {
    int b = r / 192;
    int p = r - b * 192;
    return A + ((size_t)b * 193 + 1 + p) * 768;
  }
}

template <int MODE>
__global__ __launch_bounds__(256) void gemm_kernel(
    const float* __restrict__ A, const float* __restrict__ W,
    const float* __restrict__ bias, float* __restrict__ C) {
  __shared__ float As[16][128];
  __shared__ float Bs[16][68];  // +4 pad keeps float4 alignment, breaks conflicts

  const int tid = threadIdx.x;
  const int row0 = blockIdx.y * 128;
  const int col0 = blockIdx.x * 64;
  const int tx = tid & 15;       // output col group (4 cols)
  const int ty = tid >> 4;       // output row group (8 rows)
  const int arow = tid >> 1;     // A-tile row this thread loads
  const int ak = (tid & 1) * 8;  // A-tile k offset (8 consecutive)
  const int bk = tid >> 4;       // B-tile k row
  const int bn = (tid & 15) * 4; // B-tile col (float4)

  const float* Arow = row_ptr<MODE>(A, row0 + arow);
  const float* Wp = W + (size_t)bk * 256 + col0 + bn;

  float acc[8][4] = {};

  for (int k0 = 0; k0 < 768; k0 += 16) {
    float4 a0 = *(const float4*)(Arow + k0 + ak);
    float4 a1 = *(const float4*)(Arow + k0 + ak + 4);
    float4 b0 = *(const float4*)(Wp + (size_t)k0 * 256);
    __syncthreads();
    As[ak + 0][arow] = a0.x; As[ak + 1][arow] = a0.y;
    As[ak + 2][arow] = a0.z; As[ak + 3][arow] = a0.w;
    As[ak + 4][arow] = a1.x; As[ak + 5][arow] = a1.y;
    As[ak + 6][arow] = a1.z; As[ak + 7][arow] = a1.w;
    *(float4*)&Bs[bk][bn] = b0;
    __syncthreads();
#pragma unroll
    for (int k = 0; k < 16; ++k) {
      float4 av0 = *(const float4*)&As[k][ty * 8];
      float4 av1 = *(const float4*)&As[k][ty * 8 + 4];
      float4 bv = *(const float4*)&Bs[k][tx * 4];
      float a[8] = {av0.x, av0.y, av0.z, av0.w, av1.x, av1.y, av1.z, av1.w};
      float bb[4] = {bv.x, bv.y, bv.z, bv.w};
#pragma unroll
      for (int i = 0; i < 8; ++i)
#pragma unroll
        for (int j = 0; j < 4; ++j) acc[i][j] += a[i] * bb[j];
    }
  }

  float4 bias4 = *(const float4*)(bias + col0 + tx * 4);
#pragma unroll
  for (int i = 0; i < 8; ++i) {
    int r = row0 + ty * 8 + i;
    float4 o;
    o.x = acc[i][0] + bias4.x;
    o.y = acc[i][1] + bias4.y;
    o.z = acc[i][2] + bias4.z;
    o.w = acc[i][3] + bias4.w;
    *(float4*)(C + (size_t)r * 256 + col0 + tx * 4) = o;
  }
}

// ---------------------------------------------------------------------------
// Row L2 normalization (width 256). One wave per row, 4 rows per block.
// ---------------------------------------------------------------------------
__global__ __launch_bounds__(256) void l2norm_kernel(float* __restrict__ X,
                                                     int rows) {
  int row = blockIdx.x * 4 + (threadIdx.x >> 6);
  int lane = threadIdx.x & 63;
  if (row >= rows) return;
  float4* px = (float4*)(X + (size_t)row * 256);
  float4 v = px[lane];
  float ss = v.x * v.x + v.y * v.y + v.z * v.z + v.w * v.w;
#pragma unroll
  for (int off = 1; off < 64; off <<= 1) ss += __shfl_xor(ss, off);
  float n = fmaxf(sqrtf(ss), 1e-12f);
  v.x /= n; v.y /= n; v.z /= n; v.w /= n;
  px[lane] = v;
}

// ---------------------------------------------------------------------------
// sim[b,a,p] = att[b,a,:] . pat[b,p,:]   (att,pat already normalized)
// One block (192 threads) per batch; thread owns one patch row.
// ---------------------------------------------------------------------------
__global__ __launch_bounds__(192) void sim_kernel(
    const float* __restrict__ att, const float* __restrict__ pat,
    float* __restrict__ sim) {
  const int b = blockIdx.x;
  __shared__ float attS[8][256];
  const int tid = threadIdx.x;
  for (int idx = tid; idx < 8 * 256; idx += 192)
    ((float*)attS)[idx] = att[(size_t)b * 2048 + idx];
  __syncthreads();

  const float4* prow = (const float4*)(pat + ((size_t)b * 192 + tid) * 256);
  float acc[8] = {};
#pragma unroll 4
  for (int e4 = 0; e4 < 64; ++e4) {
    float4 pv = prow[e4];
#pragma unroll
    for (int a = 0; a < 8; ++a) {
      float4 av = *((const float4*)attS[a] + e4);
      acc[a] += pv.x * av.x + pv.y * av.y + pv.z * av.z + pv.w * av.w;
    }
  }
#pragma unroll
  for (int a = 0; a < 8; ++a)
    sim[(size_t)b * 1536 + a * 192 + tid] = acc[a];
}

// ---------------------------------------------------------------------------
// Per-batch iterative masked Hungarian (Jonker-Volgenant, e-maxx form),
// K=4 rounds, n=8 rows, m=192 cols. One wave per batch. Columns live
// 3-per-lane in registers (v, minv, used); p/way/u in LDS; doubles
// throughout to mirror the float64 numpy reference.
// ---------------------------------------------------------------------------
__global__ __launch_bounds__(64) void hungarian_kernel(
    const float* __restrict__ sim, float* __restrict__ out) {
  const int b = blockIdx.x;
  const int lane = threadIdx.x;
  __shared__ float S[8][192];
  __shared__ int p[193];
  __shared__ int way[193];
  __shared__ double u[9];

  const float* simb = sim + (size_t)b * 1536;
  for (int idx = lane; idx < 1536; idx += 64) ((float*)S)[idx] = simb[idx];
  __syncthreads();

  const int j_0 = 1 + lane;        // this lane's columns (1-based)
  const int j_1 = 65 + lane;
  const int j_2 = 129 + lane;

  double total = 0.0;

  for (int round = 0; round < 4; ++round) {
    for (int idx = lane; idx < 193; idx += 64) p[idx] = 0;
    if (lane < 9) u[lane] = 0.0;
    double v0 = 0.0, v1 = 0.0, v2 = 0.0;
    __syncthreads();

    for (int i = 1; i <= 8; ++i) {
      if (lane == 0) p[0] = i;
      double m0 = 1e18, m1 = 1e18, m2 = 1e18;
      int used = 0;
      int j0 = 0;
      __syncthreads();

      while (true) {
        // mark j0 used (column 0 is implicitly used; handled via u[i] update)
        if (j0 != 0 && ((j0 - 1) & 63) == lane) used |= 1 << ((j0 - 1) >> 6);
        const int i0 = p[j0];             // uniform
        const double ui0 = u[i0];
        const float* Srow = S[i0 - 1];

        double bestv = 1e18;
        int bestj = 0x7fffffff;
        if (!(used & 1)) {
          double cur = -(double)Srow[j_0 - 1] - ui0 - v0;
          if (cur < m0) { m0 = cur; way[j_0] = j0; }
          if (m0 < bestv) { bestv = m0; bestj = j_0; }
        }
        if (!(used & 2)) {
          double cur = -(double)Srow[j_1 - 1] - ui0 - v1;
          if (cur < m1) { m1 = cur; way[j_1] = j0; }
          if (m1 < bestv) { bestv = m1; bestj = j_1; }
        }
        if (!(used & 4)) {
          double cur = -(double)Srow[j_2 - 1] - ui0 - v2;
          if (cur < m2) { m2 = cur; way[j_2] = j0; }
          if (m2 < bestv) { bestv = m2; bestj = j_2; }
        }
        // wave argmin with first-index tie-break (matches np.argmin)
#pragma unroll
        for (int off = 1; off < 64; off <<= 1) {
          double ov = __shfl_xor(bestv, off);
          int oj = __shfl_xor(bestj, off);
          if (ov < bestv || (ov == bestv && oj < bestj)) {
            bestv = ov; bestj = oj;
          }
        }
        const double delta = bestv;
        const int j1 = bestj;

        if (lane == 0) u[i] += delta;  // column 0: p[0] = i
        if (used & 1) { v0 -= delta; int pj = p[j_0]; u[pj] += delta; } else m0 -= delta;
        if (used & 2) { v1 -= delta; int pj = p[j_1]; u[pj] += delta; } else m1 -= delta;
        if (used & 4) { v2 -= delta; int pj = p[j_2]; u[pj] += delta; } else m2 -= delta;
        __syncthreads();

        j0 = j1;
        if (p[j0] == 0) break;
      }

      // augment along alternating path
      if (lane == 0) {
        int j = j0;
        while (j != 0) {
          int jp = way[j];
          p[j] = p[jp];
          j = jp;
        }
      }
      __syncthreads();
    }

    // collect round contribution and mask chosen entries
    double s = 0.0;
    {
      int pj = p[j_0];
      if (pj) { s += (double)S[pj - 1][j_0 - 1]; S[pj - 1][j_0 - 1] = -100.0f; }
      pj = p[j_1];
      if (pj) { s += (double)S[pj - 1][j_1 - 1]; S[pj - 1][j_1 - 1] = -100.0f; }
      pj = p[j_2];
      if (pj) { s += (double)S[pj - 1][j_2 - 1]; S[pj - 1][j_2 - 1] = -100.0f; }
    }
#pragma unroll
    for (int off = 1; off < 64; off <<= 1) s += __shfl_xor(s, off);
    total += s;
    __syncthreads();
  }

  if (lane == 0) out[b] = (float)(total * (1.0 / 32.0));
}

// ---------------------------------------------------------------------------
extern "C" void kernel_launch(void* const* d_in, const int* in_sizes, int n_in,
                              void* d_out, int out_size, void* d_ws,
                              size_t ws_size, hipStream_t stream) {
  const float* vf = (const float*)d_in[0];   // [256,193,768]
  const float* tf = (const float*)d_in[1];   // [256,768]
  const float* af = (const float*)d_in[2];   // [2048,768]
  // d_in[3] att_nums unused by the reference computation
  const float* Wv = (const float*)d_in[4];
  const float* bv = (const float*)d_in[5];
  const float* Wt = (const float*)d_in[6];
  const float* bt = (const float*)d_in[7];
  const float* Wp = (const float*)d_in[8];
  const float* bp = (const float*)d_in[9];
  const float* Wa = (const float*)d_in[10];
  const float* ba = (const float*)d_in[11];

  float* out = (float*)d_out;
  float* visual_out = out;               // 256*256
  float* textual_out = out + 65536;      // 256*256
  float* ls_out = out + 131072;          // 256

  char* ws = (char*)d_ws;
  float* patch = (float*)ws;                                 // 49152*256 f32 = 48 MiB
  float* attE = (float*)(ws + (size_t)49152 * 256 * 4);      // 2048*256 f32 = 2 MiB
  float* sim = (float*)(ws + (size_t)49152 * 256 * 4 + (size_t)2048 * 256 * 4); // 256*1536

  // Projections
  gemm_kernel<1><<<dim3(4, 2), 256, 0, stream>>>(vf, Wv, bv, visual_out);
  gemm_kernel<0><<<dim3(4, 2), 256, 0, stream>>>(tf, Wt, bt, textual_out);
  gemm_kernel<2><<<dim3(4, 384), 256, 0, stream>>>(vf, Wp, bp, patch);
  gemm_kernel<0><<<dim3(4, 16), 256, 0, stream>>>(af, Wa, ba, attE);

  // L2 normalize
  l2norm_kernel<<<49152 / 4, 256, 0, stream>>>(patch, 49152);
  l2norm_kernel<<<2048 / 4, 256, 0, stream>>>(attE, 2048);

  // Similarity
  sim_kernel<<<256, 192, 0, stream>>>(attE, patch, sim);

  // Hungarian + masked top-k rounds
  hungarian_kernel<<<256, 64, 0, stream>>>(sim, ls_out);
}

// Round 3
// 417.119 us; speedup vs baseline: 1.7957x; 1.7957x over previous
//
#include <hip/hip_runtime.h>
#include <hip/hip_bf16.h>

typedef float f32x4 __attribute__((ext_vector_type(4)));
typedef short s16x8 __attribute__((ext_vector_type(8)));

// ---------------------------------------------------------------------------
// helpers
// ---------------------------------------------------------------------------
__device__ __forceinline__ unsigned short f2bf(float f) {
  unsigned int x = __builtin_bit_cast(unsigned int, f);
  x += 0x7fffu + ((x >> 16) & 1u);  // RNE (inputs are finite/normal)
  return (unsigned short)(x >> 16);
}
__device__ __forceinline__ float bf2f(unsigned short u) {
  return __builtin_bit_cast(float, ((unsigned int)u) << 16);
}
__device__ __forceinline__ unsigned int packbf(float lo, float hi) {
  return (unsigned int)f2bf(lo) | ((unsigned int)f2bf(hi) << 16);
}
__device__ __forceinline__ void mfma16(f32x4& acc, s16x8 a, s16x8 b) {
  // D = A(16x32) * B(32x16) + C ; A rows = patch rows, B cols = embed cols.
  asm volatile("v_mfma_f32_16x16x32_bf16 %0, %1, %2, %0"
               : "+v"(acc)
               : "v"(a), "v"(b));
}
__device__ __forceinline__ void gload_lds16(const void* g, void* l) {
  __builtin_amdgcn_global_load_lds(
      (const __attribute__((address_space(1))) unsigned int*)g,
      (__attribute__((address_space(3))) unsigned int*)l, 16, 0, 0);
}

// ---------------------------------------------------------------------------
// prep: Wp [768][256] fp32 -> bf16, laid out so a LINEAR 16 KiB LDS fill of one
// 32-k tile yields the XOR-swizzled [col][k] layout the MFMA B-frags read.
// element (k,col): tile kt=k>>5, off = (col*64 + (k&31)*2) ^ ((col&3)<<4)
// ---------------------------------------------------------------------------
__global__ __launch_bounds__(256) void prep_wt(const float* __restrict__ W,
                                               unsigned short* __restrict__ Wt) {
  int i = blockIdx.x * 256 + threadIdx.x;  // 768*256 elements
  int k = i >> 8, col = i & 255;
  int kt = k >> 5, kl = k & 31;
  unsigned off = (unsigned)((col * 64 + kl * 2) ^ ((col & 3) << 4));
  Wt[(unsigned)(kt * 16384 + off) >> 1] = f2bf(W[i]);
}

// ---------------------------------------------------------------------------
// patch GEMM + fused bias + L2-norm, bf16 MFMA.
// C[49152 x 256] = vf[b,1+p,:768] @ Wp + bp, then row-normalized, bf16 out.
// BM=192 (one batch per block, grid 256 = 1 block/CU), BN=256, BK=32.
// 512 threads = 8 waves as 2(M) x 4(N); wave tile 96x64; acc[6][4] f32x4.
// LDS: A dbuf 2x12 KiB (XOR-swizzled), B dbuf 2x16 KiB (filled linearly from
// pre-swizzled Wt via global_load_lds).
// ---------------------------------------------------------------------------
__global__ __launch_bounds__(512, 2) void patch_gemm(
    const float* __restrict__ vf, const unsigned short* __restrict__ Wt,
    const float* __restrict__ bias, unsigned short* __restrict__ patch) {
  __shared__ char lds[57344];     // A0 @0, A1 @12288, B0 @24576, B1 @40960
  __shared__ float rssq[192];

  const int tid = threadIdx.x;
  const int lane = tid & 63, wid = tid >> 6;
  const int wm = wid >> 2, wn = wid & 3;
  const int l15 = lane & 15, l4 = lane >> 4;
  const int blk = blockIdx.x;

  if (tid < 192) rssq[tid] = 0.f;

  const float* Ag = vf + ((size_t)blk * 193 + 1) * 768;  // this batch's patches

  f32x4 acc[6][4] = {};
  f32x4 areg[3];

  // ---- staging helpers (BK=32 tile kt) ----
  auto stageA_load = [&](int kt) {
#pragma unroll
    for (int c = 0; c < 3; ++c) {
      int idx4 = c * 512 + tid;           // 1536 float4 = 192 rows x 8
      int row = idx4 >> 3, k4 = (idx4 & 7) * 4;
      areg[c] = *(const f32x4*)(Ag + (size_t)row * 768 + kt * 32 + k4);
    }
  };
  auto stageA_write = [&](int buf) {
#pragma unroll
    for (int c = 0; c < 3; ++c) {
      int idx4 = c * 512 + tid;
      int row = idx4 >> 3, k4 = (idx4 & 7) * 4;
      unsigned off = (unsigned)((row * 64 + k4 * 2) ^ ((row & 3) << 4));
      uint2 u;
      u.x = packbf(areg[c].x, areg[c].y);
      u.y = packbf(areg[c].z, areg[c].w);
      *(uint2*)(lds + buf * 12288 + off) = u;
    }
  };
  auto stageB = [&](int kt, int buf) {
#pragma unroll
    for (int it = 0; it < 2; ++it) {
      int off = wid * 2048 + it * 1024;  // wave-uniform LDS dest; HW adds lane*16
      gload_lds16((const char*)Wt + kt * 16384 + off + lane * 16,
                  lds + 24576 + buf * 16384 + off);
    }
  };
  auto compute = [&](int buf) {
    const char* Ab = lds + buf * 12288;
    const char* Bb = lds + 24576 + buf * 16384;
    const int kb = l4 * 16;  // byte offset of this lane's 8-k slice
    s16x8 af[6];
#pragma unroll
    for (int mf = 0; mf < 6; ++mf) {
      int row = wm * 96 + mf * 16 + l15;
      unsigned off = (unsigned)((row * 64 + kb) ^ ((row & 3) << 4));
      af[mf] = *(const s16x8*)(Ab + off);
    }
    s16x8 bfr[4];
#pragma unroll
    for (int nf = 0; nf < 4; ++nf) {
      int col = wn * 64 + nf * 16 + l15;
      unsigned off = (unsigned)((col * 64 + kb) ^ ((col & 3) << 4));
      bfr[nf] = *(const s16x8*)(Bb + off);
    }
#pragma unroll
    for (int mf = 0; mf < 6; ++mf)
#pragma unroll
      for (int nf = 0; nf < 4; ++nf) mfma16(acc[mf][nf], af[mf], bfr[nf]);
  };

  // ---- prologue ----
  stageA_load(0);
  stageB(0, 0);
  stageA_write(0);
  __syncthreads();

  // ---- main loop: 24 K-tiles, double-buffered ----
  int cur = 0;
  for (int kt = 0; kt < 24; ++kt) {
    if (kt < 23) {
      stageA_load(kt + 1);
      stageB(kt + 1, cur ^ 1);
    }
    compute(cur);
    if (kt < 23) stageA_write(cur ^ 1);
    __syncthreads();
    cur ^= 1;
  }

  // MFMA -> VALU hazard guard before reading acc on the vector ALU
  __builtin_amdgcn_sched_barrier(0);
  asm volatile("s_nop 7\n\ts_nop 7");
  __builtin_amdgcn_sched_barrier(0);

  // ---- epilogue: bias, row ssq (full 256-col rows), normalize, bf16 store ----
  float bcol[4];
#pragma unroll
  for (int nf = 0; nf < 4; ++nf) bcol[nf] = bias[wn * 64 + nf * 16 + l15];
#pragma unroll
  for (int mf = 0; mf < 6; ++mf)
#pragma unroll
    for (int nf = 0; nf < 4; ++nf)
#pragma unroll
      for (int j = 0; j < 4; ++j) acc[mf][nf][j] += bcol[nf];

#pragma unroll
  for (int mf = 0; mf < 6; ++mf)
#pragma unroll
    for (int j = 0; j < 4; ++j) {
      float p = 0.f;
#pragma unroll
      for (int nf = 0; nf < 4; ++nf) {
        float v = acc[mf][nf][j];
        p += v * v;
      }
#pragma unroll
      for (int m = 1; m < 16; m <<= 1) p += __shfl_xor(p, m);
      if (l15 == 0) atomicAdd(&rssq[wm * 96 + mf * 16 + l4 * 4 + j], p);
    }
  __syncthreads();

  unsigned short* outp = patch + (size_t)blk * 192 * 256;
#pragma unroll
  for (int mf = 0; mf < 6; ++mf)
#pragma unroll
    for (int j = 0; j < 4; ++j) {
      int row = wm * 96 + mf * 16 + l4 * 4 + j;
      float scale = 1.f / fmaxf(sqrtf(rssq[row]), 1e-12f);
#pragma unroll
      for (int nf = 0; nf < 4; ++nf) {
        int col = wn * 64 + nf * 16 + l15;
        outp[(size_t)row * 256 + col] = f2bf(acc[mf][nf][j] * scale);
      }
    }
}

// ---------------------------------------------------------------------------
// small fp32 GEMM for visual/textual/attribute projections (direct outputs
// stay fp32-exact). BM=32, BN=64, BK=32, 256 threads, 2x4 per thread.
// MODE 0: rows stride 768; MODE 1: visual token-0 rows (stride 193*768).
// ---------------------------------------------------------------------------
template <int MODE>
__device__ __forceinline__ const float* row_ptr(const float* A, int r) {
  if constexpr (MODE == 0) {
    return A + (size_t)r * 768;
  } else {
    return A + (size_t)r * (193 * 768);
  }
}

template <int MODE>
__global__ __launch_bounds__(256) void small_gemm(
    const float* __restrict__ A, const float* __restrict__ W,
    const float* __restrict__ bias, float* __restrict__ C) {
  __shared__ float As[32][33];
  __shared__ float Bs[32][68];
  const int tid = threadIdx.x;
  const int row0 = blockIdx.y * 32, col0 = blockIdx.x * 64;
  const int tx = tid & 15, ty = tid >> 4;
  const int lr = tid >> 3, lk = (tid & 7) * 4;
  const float* Arow = row_ptr<MODE>(A, row0 + lr);
  const int bk = tid >> 4, bn = (tid & 15) * 4;
  const float* Wp = W + (size_t)bk * 256 + col0 + bn;
  float acc[2][4] = {};

  for (int k0 = 0; k0 < 768; k0 += 32) {
    float4 a0 = *(const float4*)(Arow + k0 + lk);
    float4 b0 = *(const float4*)(Wp + (size_t)k0 * 256);
    float4 b1 = *(const float4*)(Wp + (size_t)(k0 + 16) * 256);
    __syncthreads();
    As[lk + 0][lr] = a0.x; As[lk + 1][lr] = a0.y;
    As[lk + 2][lr] = a0.z; As[lk + 3][lr] = a0.w;
    *(float4*)&Bs[bk][bn] = b0;
    *(float4*)&Bs[bk + 16][bn] = b1;
    __syncthreads();
#pragma unroll
    for (int k = 0; k < 32; ++k) {
      float a0v = As[k][ty * 2], a1v = As[k][ty * 2 + 1];
      float4 bv = *(const float4*)&Bs[k][tx * 4];
      acc[0][0] += a0v * bv.x; acc[0][1] += a0v * bv.y;
      acc[0][2] += a0v * bv.z; acc[0][3] += a0v * bv.w;
      acc[1][0] += a1v * bv.x; acc[1][1] += a1v * bv.y;
      acc[1][2] += a1v * bv.z; acc[1][3] += a1v * bv.w;
    }
  }
  float4 b4 = *(const float4*)(bias + col0 + tx * 4);
#pragma unroll
  for (int i = 0; i < 2; ++i) {
    int r = row0 + ty * 2 + i;
    float4 o;
    o.x = acc[i][0] + b4.x; o.y = acc[i][1] + b4.y;
    o.z = acc[i][2] + b4.z; o.w = acc[i][3] + b4.w;
    *(float4*)(C + (size_t)r * 256 + col0 + tx * 4) = o;
  }
}

// ---------------------------------------------------------------------------
// Row L2 normalization (width 256, fp32 in place) — attribute embeds only.
// ---------------------------------------------------------------------------
__global__ __launch_bounds__(256) void l2norm_kernel(float* __restrict__ X,
                                                     int rows) {
  int row = blockIdx.x * 4 + (threadIdx.x >> 6);
  int lane = threadIdx.x & 63;
  if (row >= rows) return;
  float4* px = (float4*)(X + (size_t)row * 256);
  float4 v = px[lane];
  float ss = v.x * v.x + v.y * v.y + v.z * v.z + v.w * v.w;
#pragma unroll
  for (int off = 1; off < 64; off <<= 1) ss += __shfl_xor(ss, off);
  float n = fmaxf(sqrtf(ss), 1e-12f);
  v.x /= n; v.y /= n; v.z /= n; v.w /= n;
  px[lane] = v;
}

// ---------------------------------------------------------------------------
// sim[b,a,p] = att[b,a,:] . pat_bf16[b,p,:]  (attS reads are wave-uniform
// broadcasts -> conflict-free). fp32 accumulate.
// ---------------------------------------------------------------------------
__global__ __launch_bounds__(192) void sim_kernel(
    const float* __restrict__ att, const unsigned short* __restrict__ pat,
    float* __restrict__ sim) {
  const int b = blockIdx.x;
  __shared__ float attS[8][256];
  const int tid = threadIdx.x;
  for (int idx = tid; idx < 2048; idx += 192)
    ((float*)attS)[idx] = att[(size_t)b * 2048 + idx];
  __syncthreads();

  const unsigned short* prow = pat + ((size_t)b * 192 + tid) * 256;
  float acc[8] = {};
  for (int e8 = 0; e8 < 32; ++e8) {
    uint4 pv = *(const uint4*)(prow + e8 * 8);
    float f[8];
    f[0] = bf2f((unsigned short)(pv.x & 0xffff)); f[1] = bf2f((unsigned short)(pv.x >> 16));
    f[2] = bf2f((unsigned short)(pv.y & 0xffff)); f[3] = bf2f((unsigned short)(pv.y >> 16));
    f[4] = bf2f((unsigned short)(pv.z & 0xffff)); f[5] = bf2f((unsigned short)(pv.z >> 16));
    f[6] = bf2f((unsigned short)(pv.w & 0xffff)); f[7] = bf2f((unsigned short)(pv.w >> 16));
#pragma unroll
    for (int a = 0; a < 8; ++a) {
      const float* ap = &attS[a][e8 * 8];
#pragma unroll
      for (int i = 0; i < 8; ++i) acc[a] += f[i] * ap[i];
    }
  }
#pragma unroll
  for (int a = 0; a < 8; ++a)
    sim[(size_t)b * 1536 + a * 192 + tid] = acc[a];
}

// ---------------------------------------------------------------------------
// Per-batch iterative masked Hungarian (Jonker-Volgenant, e-maxx form),
// K=4 rounds, n=8 rows, m=192 cols. One wave per batch; doubles to mirror
// the float64 numpy reference; argmin tie-break = first index (np.argmin).
// ---------------------------------------------------------------------------
__global__ __launch_bounds__(64) void hungarian_kernel(
    const float* __restrict__ sim, float* __restrict__ out) {
  const int b = blockIdx.x;
  const int lane = threadIdx.x;
  __shared__ float S[8][192];
  __shared__ int p[193];
  __shared__ int way[193];
  __shared__ double u[9];

  const float* simb = sim + (size_t)b * 1536;
  for (int idx = lane; idx < 1536; idx += 64) ((float*)S)[idx] = simb[idx];
  __syncthreads();

  const int j_0 = 1 + lane;
  const int j_1 = 65 + lane;
  const int j_2 = 129 + lane;

  double total = 0.0;

  for (int round = 0; round < 4; ++round) {
    for (int idx = lane; idx < 193; idx += 64) p[idx] = 0;
    if (lane < 9) u[lane] = 0.0;
    double v0 = 0.0, v1 = 0.0, v2 = 0.0;
    __syncthreads();

    for (int i = 1; i <= 8; ++i) {
      if (lane == 0) p[0] = i;
      double m0 = 1e18, m1 = 1e18, m2 = 1e18;
      int used = 0;
      int j0 = 0;
      __syncthreads();

      while (true) {
        if (j0 != 0 && ((j0 - 1) & 63) == lane) used |= 1 << ((j0 - 1) >> 6);
        const int i0 = p[j0];
        const double ui0 = u[i0];
        const float* Srow = S[i0 - 1];

        double bestv = 1e18;
        int bestj = 0x7fffffff;
        if (!(used & 1)) {
          double cur = -(double)Srow[j_0 - 1] - ui0 - v0;
          if (cur < m0) { m0 = cur; way[j_0] = j0; }
          if (m0 < bestv) { bestv = m0; bestj = j_0; }
        }
        if (!(used & 2)) {
          double cur = -(double)Srow[j_1 - 1] - ui0 - v1;
          if (cur < m1) { m1 = cur; way[j_1] = j0; }
          if (m1 < bestv) { bestv = m1; bestj = j_1; }
        }
        if (!(used & 4)) {
          double cur = -(double)Srow[j_2 - 1] - ui0 - v2;
          if (cur < m2) { m2 = cur; way[j_2] = j0; }
          if (m2 < bestv) { bestv = m2; bestj = j_2; }
        }
#pragma unroll
        for (int off = 1; off < 64; off <<= 1) {
          double ov = __shfl_xor(bestv, off);
          int oj = __shfl_xor(bestj, off);
          if (ov < bestv || (ov == bestv && oj < bestj)) {
            bestv = ov; bestj = oj;
          }
        }
        const double delta = bestv;
        const int j1 = bestj;

        if (lane == 0) u[i] += delta;
        if (used & 1) { v0 -= delta; int pj = p[j_0]; u[pj] += delta; } else m0 -= delta;
        if (used & 2) { v1 -= delta; int pj = p[j_1]; u[pj] += delta; } else m1 -= delta;
        if (used & 4) { v2 -= delta; int pj = p[j_2]; u[pj] += delta; } else m2 -= delta;
        __syncthreads();

        j0 = j1;
        if (p[j0] == 0) break;
      }

      if (lane == 0) {
        int j = j0;
        while (j != 0) {
          int jp = way[j];
          p[j] = p[jp];
          j = jp;
        }
      }
      __syncthreads();
    }

    double s = 0.0;
    {
      int pj = p[j_0];
      if (pj) { s += (double)S[pj - 1][j_0 - 1]; S[pj - 1][j_0 - 1] = -100.0f; }
      pj = p[j_1];
      if (pj) { s += (double)S[pj - 1][j_1 - 1]; S[pj - 1][j_1 - 1] = -100.0f; }
      pj = p[j_2];
      if (pj) { s += (double)S[pj - 1][j_2 - 1]; S[pj - 1][j_2 - 1] = -100.0f; }
    }
#pragma unroll
    for (int off = 1; off < 64; off <<= 1) s += __shfl_xor(s, off);
    total += s;
    __syncthreads();
  }

  if (lane == 0) out[b] = (float)(total * (1.0 / 32.0));
}

// ---------------------------------------------------------------------------
extern "C" void kernel_launch(void* const* d_in, const int* in_sizes, int n_in,
                              void* d_out, int out_size, void* d_ws,
                              size_t ws_size, hipStream_t stream) {
  const float* vf = (const float*)d_in[0];   // [256,193,768]
  const float* tf = (const float*)d_in[1];   // [256,768]
  const float* af = (const float*)d_in[2];   // [2048,768]
  const float* Wv = (const float*)d_in[4];
  const float* bv = (const float*)d_in[5];
  const float* Wt_w = (const float*)d_in[6];
  const float* bt = (const float*)d_in[7];
  const float* Wp = (const float*)d_in[8];
  const float* bp = (const float*)d_in[9];
  const float* Wa = (const float*)d_in[10];
  const float* ba = (const float*)d_in[11];

  float* out = (float*)d_out;
  float* visual_out = out;               // 256*256
  float* textual_out = out + 65536;      // 256*256
  float* ls_out = out + 131072;          // 256

  char* ws = (char*)d_ws;
  unsigned short* patch = (unsigned short*)ws;                    // 24 MiB bf16
  float* attE = (float*)(ws + (size_t)25165824);                  // 2 MiB
  float* sim = (float*)(ws + (size_t)25165824 + 2097152);         // 1.5 MiB
  unsigned short* Wt_s = (unsigned short*)(ws + (size_t)25165824 + 2097152 + 1572864);  // 384 KiB

  // weight prep for patch MFMA (must precede patch_gemm; stream-ordered)
  prep_wt<<<768, 256, 0, stream>>>(Wp, Wt_s);

  // small fp32 projections (direct outputs + attribute embeds)
  small_gemm<1><<<dim3(4, 8), 256, 0, stream>>>(vf, Wv, bv, visual_out);
  small_gemm<0><<<dim3(4, 8), 256, 0, stream>>>(tf, Wt_w, bt, textual_out);
  small_gemm<0><<<dim3(4, 64), 256, 0, stream>>>(af, Wa, ba, attE);

  // big patch projection: bf16 MFMA + fused bias + L2-norm, bf16 out
  patch_gemm<<<256, 512, 0, stream>>>(vf, Wt_s, bp, patch);

  // attribute L2 norm (fp32 in place)
  l2norm_kernel<<<512, 256, 0, stream>>>(attE, 2048);

  // similarity (fp32 att x bf16 patch)
  sim_kernel<<<256, 192, 0, stream>>>(attE, patch, sim);

  // Hungarian + masked top-k rounds
  hungarian_kernel<<<256, 64, 0, stream>>>(sim, ls_out);
}

// Round 4
// 384.091 us; speedup vs baseline: 1.9501x; 1.0860x over previous
//
#include <hip/hip_runtime.h>
#include <hip/hip_bf16.h>

typedef float f32x4 __attribute__((ext_vector_type(4)));
typedef short s16x8 __attribute__((ext_vector_type(8)));

// ---------------------------------------------------------------------------
// helpers
// ---------------------------------------------------------------------------
__device__ __forceinline__ unsigned short f2bf(float f) {
  unsigned int x = __builtin_bit_cast(unsigned int, f);
  x += 0x7fffu + ((x >> 16) & 1u);  // RNE (inputs are finite/normal)
  return (unsigned short)(x >> 16);
}
__device__ __forceinline__ float bf2f(unsigned short u) {
  return __builtin_bit_cast(float, ((unsigned int)u) << 16);
}
__device__ __forceinline__ unsigned int packbf(float lo, float hi) {
  return (unsigned int)f2bf(lo) | ((unsigned int)f2bf(hi) << 16);
}
__device__ __forceinline__ void mfma16(f32x4& acc, s16x8 a, s16x8 b) {
  asm volatile("v_mfma_f32_16x16x32_bf16 %0, %1, %2, %0"
               : "+v"(acc)
               : "v"(a), "v"(b));
}
__device__ __forceinline__ void gload_lds16(const void* g, void* l) {
  __builtin_amdgcn_global_load_lds(
      (const __attribute__((address_space(1))) unsigned int*)g,
      (__attribute__((address_space(3))) unsigned int*)l, 16, 0, 0);
}

// ---------------------------------------------------------------------------
// prep: Wp [768][256] fp32 -> bf16 pre-swizzled for linear global_load_lds
// element (k,col): tile kt=k>>5, off = (col*64 + (k&31)*2) ^ ((col&3)<<4)
// ---------------------------------------------------------------------------
__global__ __launch_bounds__(256) void prep_wt(const float* __restrict__ W,
                                               unsigned short* __restrict__ Wt) {
  int i = blockIdx.x * 256 + threadIdx.x;  // 768*256 elements
  int k = i >> 8, col = i & 255;
  int kt = k >> 5, kl = k & 31;
  unsigned off = (unsigned)((col * 64 + kl * 2) ^ ((col & 3) << 4));
  Wt[(unsigned)(kt * 16384 + off) >> 1] = f2bf(W[i]);
}

// ---------------------------------------------------------------------------
// patch GEMM + fused bias + L2-norm, bf16 MFMA. (unchanged from round 3)
// C[49152 x 256] = vf[b,1+p,:768] @ Wp + bp, row-normalized, bf16 out.
// BM=192 (one batch/block, grid 256 = 1/CU), BN=256, BK=32, 8 waves (2x4).
// ---------------------------------------------------------------------------
__global__ __launch_bounds__(512, 2) void patch_gemm(
    const float* __restrict__ vf, const unsigned short* __restrict__ Wt,
    const float* __restrict__ bias, unsigned short* __restrict__ patch) {
  __shared__ char lds[57344];     // A0 @0, A1 @12288, B0 @24576, B1 @40960
  __shared__ float rssq[192];

  const int tid = threadIdx.x;
  const int lane = tid & 63, wid = tid >> 6;
  const int wm = wid >> 2, wn = wid & 3;
  const int l15 = lane & 15, l4 = lane >> 4;
  const int blk = blockIdx.x;

  if (tid < 192) rssq[tid] = 0.f;

  const float* Ag = vf + ((size_t)blk * 193 + 1) * 768;

  f32x4 acc[6][4] = {};
  f32x4 areg[3];

  auto stageA_load = [&](int kt) {
#pragma unroll
    for (int c = 0; c < 3; ++c) {
      int idx4 = c * 512 + tid;
      int row = idx4 >> 3, k4 = (idx4 & 7) * 4;
      areg[c] = *(const f32x4*)(Ag + (size_t)row * 768 + kt * 32 + k4);
    }
  };
  auto stageA_write = [&](int buf) {
#pragma unroll
    for (int c = 0; c < 3; ++c) {
      int idx4 = c * 512 + tid;
      int row = idx4 >> 3, k4 = (idx4 & 7) * 4;
      unsigned off = (unsigned)((row * 64 + k4 * 2) ^ ((row & 3) << 4));
      uint2 u;
      u.x = packbf(areg[c].x, areg[c].y);
      u.y = packbf(areg[c].z, areg[c].w);
      *(uint2*)(lds + buf * 12288 + off) = u;
    }
  };
  auto stageB = [&](int kt, int buf) {
#pragma unroll
    for (int it = 0; it < 2; ++it) {
      int off = wid * 2048 + it * 1024;
      gload_lds16((const char*)Wt + kt * 16384 + off + lane * 16,
                  lds + 24576 + buf * 16384 + off);
    }
  };
  auto compute = [&](int buf) {
    const char* Ab = lds + buf * 12288;
    const char* Bb = lds + 24576 + buf * 16384;
    const int kb = l4 * 16;
    s16x8 af[6];
#pragma unroll
    for (int mf = 0; mf < 6; ++mf) {
      int row = wm * 96 + mf * 16 + l15;
      unsigned off = (unsigned)((row * 64 + kb) ^ ((row & 3) << 4));
      af[mf] = *(const s16x8*)(Ab + off);
    }
    s16x8 bfr[4];
#pragma unroll
    for (int nf = 0; nf < 4; ++nf) {
      int col = wn * 64 + nf * 16 + l15;
      unsigned off = (unsigned)((col * 64 + kb) ^ ((col & 3) << 4));
      bfr[nf] = *(const s16x8*)(Bb + off);
    }
#pragma unroll
    for (int mf = 0; mf < 6; ++mf)
#pragma unroll
      for (int nf = 0; nf < 4; ++nf) mfma16(acc[mf][nf], af[mf], bfr[nf]);
  };

  stageA_load(0);
  stageB(0, 0);
  stageA_write(0);
  __syncthreads();

  int cur = 0;
  for (int kt = 0; kt < 24; ++kt) {
    if (kt < 23) {
      stageA_load(kt + 1);
      stageB(kt + 1, cur ^ 1);
    }
    compute(cur);
    if (kt < 23) stageA_write(cur ^ 1);
    __syncthreads();
    cur ^= 1;
  }

  __builtin_amdgcn_sched_barrier(0);
  asm volatile("s_nop 7\n\ts_nop 7");
  __builtin_amdgcn_sched_barrier(0);

  float bcol[4];
#pragma unroll
  for (int nf = 0; nf < 4; ++nf) bcol[nf] = bias[wn * 64 + nf * 16 + l15];
#pragma unroll
  for (int mf = 0; mf < 6; ++mf)
#pragma unroll
    for (int nf = 0; nf < 4; ++nf)
#pragma unroll
      for (int j = 0; j < 4; ++j) acc[mf][nf][j] += bcol[nf];

#pragma unroll
  for (int mf = 0; mf < 6; ++mf)
#pragma unroll
    for (int j = 0; j < 4; ++j) {
      float p = 0.f;
#pragma unroll
      for (int nf = 0; nf < 4; ++nf) {
        float v = acc[mf][nf][j];
        p += v * v;
      }
#pragma unroll
      for (int m = 1; m < 16; m <<= 1) p += __shfl_xor(p, m);
      if (l15 == 0) atomicAdd(&rssq[wm * 96 + mf * 16 + l4 * 4 + j], p);
    }
  __syncthreads();

  unsigned short* outp = patch + (size_t)blk * 192 * 256;
#pragma unroll
  for (int mf = 0; mf < 6; ++mf)
#pragma unroll
    for (int j = 0; j < 4; ++j) {
      int row = wm * 96 + mf * 16 + l4 * 4 + j;
      float scale = 1.f / fmaxf(sqrtf(rssq[row]), 1e-12f);
#pragma unroll
      for (int nf = 0; nf < 4; ++nf) {
        int col = wn * 64 + nf * 16 + l15;
        outp[(size_t)row * 256 + col] = f2bf(acc[mf][nf][j] * scale);
      }
    }
}

// ---------------------------------------------------------------------------
// merged visual+textual fp32 GEMM (exact outputs). 64 blocks in y:
// y<8 -> visual rows vf[r,0,:] (stride 193*768), y>=8 -> textual rows tf.
// BM=32, BN=64, BK=32, 256 threads, 2x4 per thread.
// ---------------------------------------------------------------------------
__global__ __launch_bounds__(256) void vt_gemm(
    const float* __restrict__ vf, const float* __restrict__ tf,
    const float* __restrict__ Wv, const float* __restrict__ bv,
    const float* __restrict__ Wtx, const float* __restrict__ bt,
    float* __restrict__ out) {
  __shared__ float As[32][33];
  __shared__ float Bs[32][68];
  const bool vis = blockIdx.y < 8;
  const int row0 = (vis ? blockIdx.y : blockIdx.y - 8) * 32;
  const int col0 = blockIdx.x * 64;
  const float* A = vis ? vf : tf;
  const float* W = vis ? Wv : Wtx;
  const float* bias = vis ? bv : bt;
  float* C = vis ? out : out + 65536;
  const size_t rstride = vis ? (size_t)193 * 768 : (size_t)768;

  const int tid = threadIdx.x;
  const int tx = tid & 15, ty = tid >> 4;
  const int lr = tid >> 3, lk = (tid & 7) * 4;
  const float* Arow = A + (size_t)(row0 + lr) * rstride;
  const int bk = tid >> 4, bn = (tid & 15) * 4;
  const float* Wp = W + (size_t)bk * 256 + col0 + bn;
  float acc[2][4] = {};

  for (int k0 = 0; k0 < 768; k0 += 32) {
    float4 a0 = *(const float4*)(Arow + k0 + lk);
    float4 b0 = *(const float4*)(Wp + (size_t)k0 * 256);
    float4 b1 = *(const float4*)(Wp + (size_t)(k0 + 16) * 256);
    __syncthreads();
    As[lk + 0][lr] = a0.x; As[lk + 1][lr] = a0.y;
    As[lk + 2][lr] = a0.z; As[lk + 3][lr] = a0.w;
    *(float4*)&Bs[bk][bn] = b0;
    *(float4*)&Bs[bk + 16][bn] = b1;
    __syncthreads();
#pragma unroll
    for (int k = 0; k < 32; ++k) {
      float a0v = As[k][ty * 2], a1v = As[k][ty * 2 + 1];
      float4 bv4 = *(const float4*)&Bs[k][tx * 4];
      acc[0][0] += a0v * bv4.x; acc[0][1] += a0v * bv4.y;
      acc[0][2] += a0v * bv4.z; acc[0][3] += a0v * bv4.w;
      acc[1][0] += a1v * bv4.x; acc[1][1] += a1v * bv4.y;
      acc[1][2] += a1v * bv4.z; acc[1][3] += a1v * bv4.w;
    }
  }
  float4 b4 = *(const float4*)(bias + col0 + tx * 4);
#pragma unroll
  for (int i = 0; i < 2; ++i) {
    int r = row0 + ty * 2 + i;
    float4 o;
    o.x = acc[i][0] + b4.x; o.y = acc[i][1] + b4.y;
    o.z = acc[i][2] + b4.z; o.w = acc[i][3] + b4.w;
    *(float4*)(C + (size_t)r * 256 + col0 + tx * 4) = o;
  }
}

// ---------------------------------------------------------------------------
// attribute fp32 GEMM (rows stride 768). BM=32,BN=64. (round-3 small_gemm)
// ---------------------------------------------------------------------------
__global__ __launch_bounds__(256) void att_gemm(
    const float* __restrict__ A, const float* __restrict__ W,
    const float* __restrict__ bias, float* __restrict__ C) {
  __shared__ float As[32][33];
  __shared__ float Bs[32][68];
  const int tid = threadIdx.x;
  const int row0 = blockIdx.y * 32, col0 = blockIdx.x * 64;
  const int tx = tid & 15, ty = tid >> 4;
  const int lr = tid >> 3, lk = (tid & 7) * 4;
  const float* Arow = A + (size_t)(row0 + lr) * 768;
  const int bk = tid >> 4, bn = (tid & 15) * 4;
  const float* Wp = W + (size_t)bk * 256 + col0 + bn;
  float acc[2][4] = {};

  for (int k0 = 0; k0 < 768; k0 += 32) {
    float4 a0 = *(const float4*)(Arow + k0 + lk);
    float4 b0 = *(const float4*)(Wp + (size_t)k0 * 256);
    float4 b1 = *(const float4*)(Wp + (size_t)(k0 + 16) * 256);
    __syncthreads();
    As[lk + 0][lr] = a0.x; As[lk + 1][lr] = a0.y;
    As[lk + 2][lr] = a0.z; As[lk + 3][lr] = a0.w;
    *(float4*)&Bs[bk][bn] = b0;
    *(float4*)&Bs[bk + 16][bn] = b1;
    __syncthreads();
#pragma unroll
    for (int k = 0; k < 32; ++k) {
      float a0v = As[k][ty * 2], a1v = As[k][ty * 2 + 1];
      float4 bv4 = *(const float4*)&Bs[k][tx * 4];
      acc[0][0] += a0v * bv4.x; acc[0][1] += a0v * bv4.y;
      acc[0][2] += a0v * bv4.z; acc[0][3] += a0v * bv4.w;
      acc[1][0] += a1v * bv4.x; acc[1][1] += a1v * bv4.y;
      acc[1][2] += a1v * bv4.z; acc[1][3] += a1v * bv4.w;
    }
  }
  float4 b4 = *(const float4*)(bias + col0 + tx * 4);
#pragma unroll
  for (int i = 0; i < 2; ++i) {
    int r = row0 + ty * 2 + i;
    float4 o;
    o.x = acc[i][0] + b4.x; o.y = acc[i][1] + b4.y;
    o.z = acc[i][2] + b4.z; o.w = acc[i][3] + b4.w;
    *(float4*)(C + (size_t)r * 256 + col0 + tx * 4) = o;
  }
}

// ---------------------------------------------------------------------------
// Row L2 normalization (width 256, fp32 in place) — attribute embeds.
// ---------------------------------------------------------------------------
__global__ __launch_bounds__(256) void l2norm_kernel(float* __restrict__ X,
                                                     int rows) {
  int row = blockIdx.x * 4 + (threadIdx.x >> 6);
  int lane = threadIdx.x & 63;
  if (row >= rows) return;
  float4* px = (float4*)(X + (size_t)row * 256);
  float4 v = px[lane];
  float ss = v.x * v.x + v.y * v.y + v.z * v.z + v.w * v.w;
#pragma unroll
  for (int off = 1; off < 64; off <<= 1) ss += __shfl_xor(ss, off);
  float n = fmaxf(sqrtf(ss), 1e-12f);
  v.x /= n; v.y /= n; v.z /= n; v.w /= n;
  px[lane] = v;
}

// ---------------------------------------------------------------------------
// sim[b,a,p] = att[b,a,:] . pat_bf16[b,p,:]
// ---------------------------------------------------------------------------
__global__ __launch_bounds__(192) void sim_kernel(
    const float* __restrict__ att, const unsigned short* __restrict__ pat,
    float* __restrict__ sim) {
  const int b = blockIdx.x;
  __shared__ float attS[8][256];
  const int tid = threadIdx.x;
  for (int idx = tid; idx < 2048; idx += 192)
    ((float*)attS)[idx] = att[(size_t)b * 2048 + idx];
  __syncthreads();

  const unsigned short* prow = pat + ((size_t)b * 192 + tid) * 256;
  float acc[8] = {};
  for (int e8 = 0; e8 < 32; ++e8) {
    uint4 pv = *(const uint4*)(prow + e8 * 8);
    float f[8];
    f[0] = bf2f((unsigned short)(pv.x & 0xffff)); f[1] = bf2f((unsigned short)(pv.x >> 16));
    f[2] = bf2f((unsigned short)(pv.y & 0xffff)); f[3] = bf2f((unsigned short)(pv.y >> 16));
    f[4] = bf2f((unsigned short)(pv.z & 0xffff)); f[5] = bf2f((unsigned short)(pv.z >> 16));
    f[6] = bf2f((unsigned short)(pv.w & 0xffff)); f[7] = bf2f((unsigned short)(pv.w >> 16));
#pragma unroll
    for (int a = 0; a < 8; ++a) {
      const float* ap = &attS[a][e8 * 8];
#pragma unroll
      for (int i = 0; i < 8; ++i) acc[a] += f[i] * ap[i];
    }
  }
#pragma unroll
  for (int a = 0; a < 8; ++a)
    sim[(size_t)b * 1536 + a * 192 + tid] = acc[a];
}

// ---------------------------------------------------------------------------
// Hungarian v2: register-resident Jonker-Volgenant. Same f64 arithmetic, same
// op order as the proven v1 — but S (24 VGPR), u[1..8] (replicated regs),
// and per-lane p cache keep the Dijkstra inner loop free of LDS reads and
// barriers. The wave argmin carries (value, col, p[col]) so the matched row
// is known in-register. LDS (p/way) only touched at augmentation.
// ---------------------------------------------------------------------------
__global__ __launch_bounds__(64) void hungarian_kernel(
    const float* __restrict__ sim, float* __restrict__ out) {
  const int b = blockIdx.x;
  const int lane = threadIdx.x;
  __shared__ int p[193];
  __shared__ int way[193];

  // Sr[r][c] = sim[b][r][lane + c*64]
  float Sr[8][3];
  const float* simb = sim + (size_t)b * 1536;
#pragma unroll
  for (int r = 0; r < 8; ++r)
#pragma unroll
    for (int c = 0; c < 3; ++c) Sr[r][c] = simb[r * 192 + c * 64 + lane];

  double total = 0.0;

  for (int round = 0; round < 4; ++round) {
    for (int idx = lane; idx < 193; idx += 64) p[idx] = 0;
    double u1 = 0, u2 = 0, u3 = 0, u4 = 0, u5 = 0, u6 = 0, u7 = 0, u8 = 0;
    double v0 = 0.0, v1 = 0.0, v2 = 0.0;
    int pc0 = 0, pc1 = 0, pc2 = 0;  // cached p[1+lane], p[65+lane], p[129+lane]
    __syncthreads();

    for (int i = 1; i <= 8; ++i) {
      if (lane == 0) p[0] = i;
      double m0 = 1e18, m1 = 1e18, m2 = 1e18;
      int used = 0;
      int j0 = 0;
      int pj0 = i;  // p[0] = i
      int rowmask = 0;

      while (true) {
        rowmask |= 1 << pj0;
        if (j0 != 0 && ((j0 - 1) & 63) == lane) used |= 1 << ((j0 - 1) >> 6);
        const int i0 = __builtin_amdgcn_readfirstlane(pj0);

        double ui0 = u1;
        if (i0 == 2) ui0 = u2;
        if (i0 == 3) ui0 = u3;
        if (i0 == 4) ui0 = u4;
        if (i0 == 5) ui0 = u5;
        if (i0 == 6) ui0 = u6;
        if (i0 == 7) ui0 = u7;
        if (i0 == 8) ui0 = u8;

        float s0 = Sr[0][0], s1 = Sr[0][1], s2 = Sr[0][2];
#pragma unroll
        for (int r = 1; r < 8; ++r)
          if (i0 == r + 1) { s0 = Sr[r][0]; s1 = Sr[r][1]; s2 = Sr[r][2]; }

        double bestv = 1e18;
        int bestj = 0x7fffffff;
        int bestpj = 0;
        if (!(used & 1)) {
          double cur = -(double)s0 - ui0 - v0;
          if (cur < m0) { m0 = cur; way[1 + lane] = j0; }
          if (m0 < bestv) { bestv = m0; bestj = 1 + lane; bestpj = pc0; }
        }
        if (!(used & 2)) {
          double cur = -(double)s1 - ui0 - v1;
          if (cur < m1) { m1 = cur; way[65 + lane] = j0; }
          if (m1 < bestv) { bestv = m1; bestj = 65 + lane; bestpj = pc1; }
        }
        if (!(used & 4)) {
          double cur = -(double)s2 - ui0 - v2;
          if (cur < m2) { m2 = cur; way[129 + lane] = j0; }
          if (m2 < bestv) { bestv = m2; bestj = 129 + lane; bestpj = pc2; }
        }
#pragma unroll
        for (int off = 1; off < 64; off <<= 1) {
          double ov = __shfl_xor(bestv, off);
          int oj = __shfl_xor(bestj, off);
          int opj = __shfl_xor(bestpj, off);
          if (ov < bestv || (ov == bestv && oj < bestj)) {
            bestv = ov; bestj = oj; bestpj = opj;
          }
        }
        const double delta = bestv;

        if (rowmask & (1 << 1)) u1 += delta;
        if (rowmask & (1 << 2)) u2 += delta;
        if (rowmask & (1 << 3)) u3 += delta;
        if (rowmask & (1 << 4)) u4 += delta;
        if (rowmask & (1 << 5)) u5 += delta;
        if (rowmask & (1 << 6)) u6 += delta;
        if (rowmask & (1 << 7)) u7 += delta;
        if (rowmask & (1 << 8)) u8 += delta;
        if (used & 1) v0 -= delta; else m0 -= delta;
        if (used & 2) v1 -= delta; else m1 -= delta;
        if (used & 4) v2 -= delta; else m2 -= delta;

        j0 = bestj;
        pj0 = bestpj;
        if (pj0 == 0) break;
      }

      __syncthreads();  // way[] writes -> lane 0
      if (lane == 0) {
        int j = j0;
        while (j != 0) {
          int jp = way[j];
          p[j] = p[jp];
          j = jp;
        }
      }
      __syncthreads();  // p[] -> all lanes
      pc0 = p[1 + lane];
      pc1 = p[65 + lane];
      pc2 = p[129 + lane];
    }

    // collect matched sims for this round and mask them
    double s = 0.0;
    if (pc0) {
#pragma unroll
      for (int r = 0; r < 8; ++r)
        if (pc0 == r + 1) { s += (double)Sr[r][0]; Sr[r][0] = -100.f; }
    }
    if (pc1) {
#pragma unroll
      for (int r = 0; r < 8; ++r)
        if (pc1 == r + 1) { s += (double)Sr[r][1]; Sr[r][1] = -100.f; }
    }
    if (pc2) {
#pragma unroll
      for (int r = 0; r < 8; ++r)
        if (pc2 == r + 1) { s += (double)Sr[r][2]; Sr[r][2] = -100.f; }
    }
#pragma unroll
    for (int off = 1; off < 64; off <<= 1) s += __shfl_xor(s, off);
    total += s;
    __syncthreads();
  }

  if (lane == 0) out[b] = (float)(total * (1.0 / 32.0));
}

// ---------------------------------------------------------------------------
extern "C" void kernel_launch(void* const* d_in, const int* in_sizes, int n_in,
                              void* d_out, int out_size, void* d_ws,
                              size_t ws_size, hipStream_t stream) {
  const float* vf = (const float*)d_in[0];   // [256,193,768]
  const float* tf = (const float*)d_in[1];   // [256,768]
  const float* af = (const float*)d_in[2];   // [2048,768]
  const float* Wv = (const float*)d_in[4];
  const float* bv = (const float*)d_in[5];
  const float* Wtx = (const float*)d_in[6];
  const float* bt = (const float*)d_in[7];
  const float* Wp = (const float*)d_in[8];
  const float* bp = (const float*)d_in[9];
  const float* Wa = (const float*)d_in[10];
  const float* ba = (const float*)d_in[11];

  float* out = (float*)d_out;
  float* visual_out = out;               // 256*256
  float* ls_out = out + 131072;          // 256

  char* ws = (char*)d_ws;
  unsigned short* patch = (unsigned short*)ws;                    // 24 MiB bf16
  float* attE = (float*)(ws + (size_t)25165824);                  // 2 MiB
  float* sim = (float*)(ws + (size_t)25165824 + 2097152);         // 1.5 MiB
  unsigned short* Wt_s = (unsigned short*)(ws + (size_t)25165824 + 2097152 + 1572864);  // 384 KiB

  // weight prep for patch MFMA
  prep_wt<<<768, 256, 0, stream>>>(Wp, Wt_s);

  // merged visual+textual fp32 projections (exact outputs)
  vt_gemm<<<dim3(4, 16), 256, 0, stream>>>(vf, tf, Wv, bv, Wtx, bt, visual_out);

  // attribute fp32 projection
  att_gemm<<<dim3(4, 64), 256, 0, stream>>>(af, Wa, ba, attE);

  // attribute L2 norm
  l2norm_kernel<<<512, 256, 0, stream>>>(attE, 2048);

  // big patch projection: bf16 MFMA + fused bias + L2-norm, bf16 out
  patch_gemm<<<256, 512, 0, stream>>>(vf, Wt_s, bp, patch);

  // similarity (fp32 att x bf16 patch)
  sim_kernel<<<256, 192, 0, stream>>>(attE, patch, sim);

  // Hungarian + masked top-k rounds
  hungarian_kernel<<<256, 64, 0, stream>>>(sim, ls_out);
}

// Round 7
// 383.275 us; speedup vs baseline: 1.9543x; 1.0021x over previous
//
#include <hip/hip_runtime.h>
#include <hip/hip_bf16.h>

typedef float f32x4 __attribute__((ext_vector_type(4)));
typedef short s16x8 __attribute__((ext_vector_type(8)));

// ---------------------------------------------------------------------------
// helpers
// ---------------------------------------------------------------------------
__device__ __forceinline__ unsigned short f2bf(float f) {
  unsigned int x = __builtin_bit_cast(unsigned int, f);
  x += 0x7fffu + ((x >> 16) & 1u);  // RNE (inputs are finite/normal)
  return (unsigned short)(x >> 16);
}
__device__ __forceinline__ float bf2f(unsigned int u) {
  return __builtin_bit_cast(float, (u & 0xffffu) << 16);
}
__device__ __forceinline__ unsigned int packbf(float lo, float hi) {
  return (unsigned int)f2bf(lo) | ((unsigned int)f2bf(hi) << 16);
}
__device__ __forceinline__ void mfma16(f32x4& acc, s16x8 a, s16x8 b) {
  asm volatile("v_mfma_f32_16x16x32_bf16 %0, %1, %2, %0"
               : "+v"(acc)
               : "v"(a), "v"(b));
}
__device__ __forceinline__ void gload_lds16(const void* g, void* l) {
  __builtin_amdgcn_global_load_lds(
      (const __attribute__((address_space(1))) unsigned int*)g,
      (__attribute__((address_space(3))) unsigned int*)l, 16, 0, 0);
}

// ---------------------------------------------------------------------------
// prep: Wp [768][256] fp32 -> bf16 pre-swizzled for linear global_load_lds
// element (k,col): tile kt=k>>5, off = (col*64 + (k&31)*2) ^ ((col&3)<<4)
// ---------------------------------------------------------------------------
__global__ __launch_bounds__(256) void prep_wt(const float* __restrict__ W,
                                               unsigned short* __restrict__ Wt) {
  int i = blockIdx.x * 256 + threadIdx.x;  // 768*256 elements
  int k = i >> 8, col = i & 255;
  int kt = k >> 5, kl = k & 31;
  unsigned off = (unsigned)((col * 64 + kl * 2) ^ ((col & 3) << 4));
  Wt[(unsigned)(kt * 16384 + off) >> 1] = f2bf(W[i]);
}

// ---------------------------------------------------------------------------
// patch GEMM + fused bias + L2-norm, bf16 MFMA. (proven, unchanged)
// C[49152 x 256] = vf[b,1+p,:768] @ Wp + bp, row-normalized, bf16 out.
// BM=192 (one batch/block, grid 256 = 1/CU), BN=256, BK=32, 8 waves (2x4).
// ---------------------------------------------------------------------------
__global__ __launch_bounds__(512, 2) void patch_gemm(
    const float* __restrict__ vf, const unsigned short* __restrict__ Wt,
    const float* __restrict__ bias, unsigned short* __restrict__ patch) {
  __shared__ char lds[57344];     // A0 @0, A1 @12288, B0 @24576, B1 @40960
  __shared__ float rssq[192];

  const int tid = threadIdx.x;
  const int lane = tid & 63, wid = tid >> 6;
  const int wm = wid >> 2, wn = wid & 3;
  const int l15 = lane & 15, l4 = lane >> 4;
  const int blk = blockIdx.x;

  if (tid < 192) rssq[tid] = 0.f;

  const float* Ag = vf + ((size_t)blk * 193 + 1) * 768;

  f32x4 acc[6][4] = {};
  f32x4 areg[3];

  auto stageA_load = [&](int kt) {
#pragma unroll
    for (int c = 0; c < 3; ++c) {
      int idx4 = c * 512 + tid;
      int row = idx4 >> 3, k4 = (idx4 & 7) * 4;
      areg[c] = *(const f32x4*)(Ag + (size_t)row * 768 + kt * 32 + k4);
    }
  };
  auto stageA_write = [&](int buf) {
#pragma unroll
    for (int c = 0; c < 3; ++c) {
      int idx4 = c * 512 + tid;
      int row = idx4 >> 3, k4 = (idx4 & 7) * 4;
      unsigned off = (unsigned)((row * 64 + k4 * 2) ^ ((row & 3) << 4));
      uint2 u;
      u.x = packbf(areg[c].x, areg[c].y);
      u.y = packbf(areg[c].z, areg[c].w);
      *(uint2*)(lds + buf * 12288 + off) = u;
    }
  };
  auto stageB = [&](int kt, int buf) {
#pragma unroll
    for (int it = 0; it < 2; ++it) {
      int off = wid * 2048 + it * 1024;
      gload_lds16((const char*)Wt + kt * 16384 + off + lane * 16,
                  lds + 24576 + buf * 16384 + off);
    }
  };
  auto compute = [&](int buf) {
    const char* Ab = lds + buf * 12288;
    const char* Bb = lds + 24576 + buf * 16384;
    const int kb = l4 * 16;
    s16x8 af[6];
#pragma unroll
    for (int mf = 0; mf < 6; ++mf) {
      int row = wm * 96 + mf * 16 + l15;
      unsigned off = (unsigned)((row * 64 + kb) ^ ((row & 3) << 4));
      af[mf] = *(const s16x8*)(Ab + off);
    }
    s16x8 bfr[4];
#pragma unroll
    for (int nf = 0; nf < 4; ++nf) {
      int col = wn * 64 + nf * 16 + l15;
      unsigned off = (unsigned)((col * 64 + kb) ^ ((col & 3) << 4));
      bfr[nf] = *(const s16x8*)(Bb + off);
    }
#pragma unroll
    for (int mf = 0; mf < 6; ++mf)
#pragma unroll
      for (int nf = 0; nf < 4; ++nf) mfma16(acc[mf][nf], af[mf], bfr[nf]);
  };

  stageA_load(0);
  stageB(0, 0);
  stageA_write(0);
  __syncthreads();

  int cur = 0;
  for (int kt = 0; kt < 24; ++kt) {
    if (kt < 23) {
      stageA_load(kt + 1);
      stageB(kt + 1, cur ^ 1);
    }
    compute(cur);
    if (kt < 23) stageA_write(cur ^ 1);
    __syncthreads();
    cur ^= 1;
  }

  __builtin_amdgcn_sched_barrier(0);
  asm volatile("s_nop 7\n\ts_nop 7");
  __builtin_amdgcn_sched_barrier(0);

  float bcol[4];
#pragma unroll
  for (int nf = 0; nf < 4; ++nf) bcol[nf] = bias[wn * 64 + nf * 16 + l15];
#pragma unroll
  for (int mf = 0; mf < 6; ++mf)
#pragma unroll
    for (int nf = 0; nf < 4; ++nf)
#pragma unroll
      for (int j = 0; j < 4; ++j) acc[mf][nf][j] += bcol[nf];

#pragma unroll
  for (int mf = 0; mf < 6; ++mf)
#pragma unroll
    for (int j = 0; j < 4; ++j) {
      float p = 0.f;
#pragma unroll
      for (int nf = 0; nf < 4; ++nf) {
        float v = acc[mf][nf][j];
        p += v * v;
      }
#pragma unroll
      for (int m = 1; m < 16; m <<= 1) p += __shfl_xor(p, m);
      if (l15 == 0) atomicAdd(&rssq[wm * 96 + mf * 16 + l4 * 4 + j], p);
    }
  __syncthreads();

  unsigned short* outp = patch + (size_t)blk * 192 * 256;
#pragma unroll
  for (int mf = 0; mf < 6; ++mf)
#pragma unroll
    for (int j = 0; j < 4; ++j) {
      int row = wm * 96 + mf * 16 + l4 * 4 + j;
      float scale = 1.f / fmaxf(sqrtf(rssq[row]), 1e-12f);
#pragma unroll
      for (int nf = 0; nf < 4; ++nf) {
        int col = wn * 64 + nf * 16 + l15;
        outp[(size_t)row * 256 + col] = f2bf(acc[mf][nf][j] * scale);
      }
    }
}

// ---------------------------------------------------------------------------
// merged visual+textual fp32 GEMM (exact outputs). (proven, unchanged)
// ---------------------------------------------------------------------------
__global__ __launch_bounds__(256) void vt_gemm(
    const float* __restrict__ vf, const float* __restrict__ tf,
    const float* __restrict__ Wv, const float* __restrict__ bv,
    const float* __restrict__ Wtx, const float* __restrict__ bt,
    float* __restrict__ out) {
  __shared__ float As[32][33];
  __shared__ float Bs[32][68];
  const bool vis = blockIdx.y < 8;
  const int row0 = (vis ? blockIdx.y : blockIdx.y - 8) * 32;
  const int col0 = blockIdx.x * 64;
  const float* A = vis ? vf : tf;
  const float* W = vis ? Wv : Wtx;
  const float* bias = vis ? bv : bt;
  float* C = vis ? out : out + 65536;
  const size_t rstride = vis ? (size_t)193 * 768 : (size_t)768;

  const int tid = threadIdx.x;
  const int tx = tid & 15, ty = tid >> 4;
  const int lr = tid >> 3, lk = (tid & 7) * 4;
  const float* Arow = A + (size_t)(row0 + lr) * rstride;
  const int bk = tid >> 4, bn = (tid & 15) * 4;
  const float* Wp = W + (size_t)bk * 256 + col0 + bn;
  float acc[2][4] = {};

  for (int k0 = 0; k0 < 768; k0 += 32) {
    float4 a0 = *(const float4*)(Arow + k0 + lk);
    float4 b0 = *(const float4*)(Wp + (size_t)k0 * 256);
    float4 b1 = *(const float4*)(Wp + (size_t)(k0 + 16) * 256);
    __syncthreads();
    As[lk + 0][lr] = a0.x; As[lk + 1][lr] = a0.y;
    As[lk + 2][lr] = a0.z; As[lk + 3][lr] = a0.w;
    *(float4*)&Bs[bk][bn] = b0;
    *(float4*)&Bs[bk + 16][bn] = b1;
    __syncthreads();
#pragma unroll
    for (int k = 0; k < 32; ++k) {
      float a0v = As[k][ty * 2], a1v = As[k][ty * 2 + 1];
      float4 bv4 = *(const float4*)&Bs[k][tx * 4];
      acc[0][0] += a0v * bv4.x; acc[0][1] += a0v * bv4.y;
      acc[0][2] += a0v * bv4.z; acc[0][3] += a0v * bv4.w;
      acc[1][0] += a1v * bv4.x; acc[1][1] += a1v * bv4.y;
      acc[1][2] += a1v * bv4.z; acc[1][3] += a1v * bv4.w;
    }
  }
  float4 b4 = *(const float4*)(bias + col0 + tx * 4);
#pragma unroll
  for (int i = 0; i < 2; ++i) {
    int r = row0 + ty * 2 + i;
    float4 o;
    o.x = acc[i][0] + b4.x; o.y = acc[i][1] + b4.y;
    o.z = acc[i][2] + b4.z; o.w = acc[i][3] + b4.w;
    *(float4*)(C + (size_t)r * 256 + col0 + tx * 4) = o;
  }
}

// ---------------------------------------------------------------------------
// simatt: per-batch fused att-projection (VALU, Wa from L2) + bias + L2norm
//         + sim (coalesced, wave-per-row). Uniform control flow, standard
//         __syncthreads() only. sim written to workspace (global).
// One block per batch, 512 threads (8 waves), grid 256 = 1 block/CU.
// ---------------------------------------------------------------------------
__global__ __launch_bounds__(512, 2) void simatt(
    const float* __restrict__ af, const float* __restrict__ Wa,
    const float* __restrict__ ba, const unsigned short* __restrict__ pat,
    float* __restrict__ sim) {
  const int b = blockIdx.x;
  const int tid = threadIdx.x;
  const int lane = tid & 63, wid = tid >> 6;

  __shared__ float af_s[8][768];      // 24 KiB  raw attribute rows
  __shared__ float part[8][8][256];   // 64 KiB  per-wave K-partials
  __shared__ float att_s[8][256];     //  8 KiB  att embeds (bias added)
  __shared__ float rnorm_s[8];

  // ---- stage af rows (8 x 768 f32, coalesced) ----
#pragma unroll
  for (int c = 0; c < 3; ++c) {
    int idx = c * 512 + tid;               // float4 index, 1536 total
    int row = idx / 192, k4 = (idx % 192) * 4;
    *(float4*)&af_s[row][k4] =
        *(const float4*)(af + ((size_t)(b * 8 + row)) * 768 + k4);
  }
  __syncthreads();

  // ---- att GEMM: wave w covers k in [w*96, w*96+96), lane owns 4 cols ----
  {
    const int c0 = lane * 4;
    const int kbase = wid * 96;
    float pacc[8][4] = {};
    for (int kk = 0; kk < 96; kk += 4) {
      int k = kbase + kk;
      float4 w0 = *(const float4*)(Wa + (size_t)(k + 0) * 256 + c0);
      float4 w1 = *(const float4*)(Wa + (size_t)(k + 1) * 256 + c0);
      float4 w2 = *(const float4*)(Wa + (size_t)(k + 2) * 256 + c0);
      float4 w3 = *(const float4*)(Wa + (size_t)(k + 3) * 256 + c0);
#pragma unroll
      for (int a = 0; a < 8; ++a) {
        float4 a4 = *(const float4*)&af_s[a][k];   // wave-uniform: broadcast
        pacc[a][0] += a4.x * w0.x + a4.y * w1.x + a4.z * w2.x + a4.w * w3.x;
        pacc[a][1] += a4.x * w0.y + a4.y * w1.y + a4.z * w2.y + a4.w * w3.y;
        pacc[a][2] += a4.x * w0.z + a4.y * w1.z + a4.z * w2.z + a4.w * w3.z;
        pacc[a][3] += a4.x * w0.w + a4.y * w1.w + a4.z * w2.w + a4.w * w3.w;
      }
    }
#pragma unroll
    for (int a = 0; a < 8; ++a) *(float4*)&part[wid][a][c0] = *(float4*)pacc[a];
  }
  __syncthreads();

  // ---- combine partials + bias ----
  {
    int c = tid & 255;
    int ah = (tid >> 8) * 4;
#pragma unroll
    for (int q = 0; q < 4; ++q) {
      int a = ah + q;
      float e = ba[c];
#pragma unroll
      for (int w = 0; w < 8; ++w) e += part[w][a][c];
      att_s[a][c] = e;
    }
  }
  __syncthreads();

  // ---- row L2 norm: wave w handles att row w ----
  {
    float4 v = *(const float4*)&att_s[wid][lane * 4];
    float ss = v.x * v.x + v.y * v.y + v.z * v.z + v.w * v.w;
#pragma unroll
    for (int m = 1; m < 64; m <<= 1) ss += __shfl_xor(ss, m);
    if (lane == 0) rnorm_s[wid] = 1.f / fmaxf(sqrtf(ss), 1e-12f);
  }
  __syncthreads();

  // ---- normalized att into registers: attreg[a][i] = att[a][lane*4+i] ----
  float attreg[8][4];
#pragma unroll
  for (int a = 0; a < 8; ++a) {
    float4 v = *(const float4*)&att_s[a][lane * 4];
    float rn = rnorm_s[a];
    attreg[a][0] = v.x * rn; attreg[a][1] = v.y * rn;
    attreg[a][2] = v.z * rn; attreg[a][3] = v.w * rn;
  }

  // ---- sim: wave w computes patch rows [w*24, w*24+24); direct global out ----
  const unsigned short* patb = pat + (size_t)b * 192 * 256;
  float* simb = sim + (size_t)b * 1536;
  for (int pr = 0; pr < 24; ++pr) {
    int prow = wid * 24 + pr;
    uint2 pv = *(const uint2*)(patb + (size_t)prow * 256 + lane * 4);
    float f0 = bf2f(pv.x), f1 = bf2f(pv.x >> 16);
    float f2 = bf2f(pv.y), f3 = bf2f(pv.y >> 16);
    float acc[8];
#pragma unroll
    for (int a = 0; a < 8; ++a)
      acc[a] = f0 * attreg[a][0] + f1 * attreg[a][1] +
               f2 * attreg[a][2] + f3 * attreg[a][3];
#pragma unroll
    for (int a = 0; a < 8; ++a)
#pragma unroll
      for (int m = 1; m < 64; m <<= 1) acc[a] += __shfl_xor(acc[a], m);
    float sel = acc[0];
#pragma unroll
    for (int a = 1; a < 8; ++a)
      if (lane == a) sel = acc[a];
    if (lane < 8) simb[lane * 192 + prow] = sel;
  }
}

// ---------------------------------------------------------------------------
// Hungarian v2 (EXACT round-4-proven kernel): register-resident
// Jonker-Volgenant, one 64-thread block per batch, __syncthreads() sync.
// ---------------------------------------------------------------------------
__global__ __launch_bounds__(64) void hungarian_kernel(
    const float* __restrict__ sim, float* __restrict__ out) {
  const int b = blockIdx.x;
  const int lane = threadIdx.x;
  __shared__ int p[193];
  __shared__ int way[193];

  // Sr[r][c] = sim[b][r][lane + c*64]
  float Sr[8][3];
  const float* simb = sim + (size_t)b * 1536;
#pragma unroll
  for (int r = 0; r < 8; ++r)
#pragma unroll
    for (int c = 0; c < 3; ++c) Sr[r][c] = simb[r * 192 + c * 64 + lane];

  double total = 0.0;

  for (int round = 0; round < 4; ++round) {
    for (int idx = lane; idx < 193; idx += 64) p[idx] = 0;
    double u1 = 0, u2 = 0, u3 = 0, u4 = 0, u5 = 0, u6 = 0, u7 = 0, u8 = 0;
    double v0 = 0.0, v1 = 0.0, v2 = 0.0;
    int pc0 = 0, pc1 = 0, pc2 = 0;  // cached p[1+lane], p[65+lane], p[129+lane]
    __syncthreads();

    for (int i = 1; i <= 8; ++i) {
      if (lane == 0) p[0] = i;
      double m0 = 1e18, m1 = 1e18, m2 = 1e18;
      int used = 0;
      int j0 = 0;
      int pj0 = i;  // p[0] = i
      int rowmask = 0;

      while (true) {
        rowmask |= 1 << pj0;
        if (j0 != 0 && ((j0 - 1) & 63) == lane) used |= 1 << ((j0 - 1) >> 6);
        const int i0 = __builtin_amdgcn_readfirstlane(pj0);

        double ui0 = u1;
        if (i0 == 2) ui0 = u2;
        if (i0 == 3) ui0 = u3;
        if (i0 == 4) ui0 = u4;
        if (i0 == 5) ui0 = u5;
        if (i0 == 6) ui0 = u6;
        if (i0 == 7) ui0 = u7;
        if (i0 == 8) ui0 = u8;

        float s0 = Sr[0][0], s1 = Sr[0][1], s2 = Sr[0][2];
#pragma unroll
        for (int r = 1; r < 8; ++r)
          if (i0 == r + 1) { s0 = Sr[r][0]; s1 = Sr[r][1]; s2 = Sr[r][2]; }

        double bestv = 1e18;
        int bestj = 0x7fffffff;
        int bestpj = 0;
        if (!(used & 1)) {
          double cur = -(double)s0 - ui0 - v0;
          if (cur < m0) { m0 = cur; way[1 + lane] = j0; }
          if (m0 < bestv) { bestv = m0; bestj = 1 + lane; bestpj = pc0; }
        }
        if (!(used & 2)) {
          double cur = -(double)s1 - ui0 - v1;
          if (cur < m1) { m1 = cur; way[65 + lane] = j0; }
          if (m1 < bestv) { bestv = m1; bestj = 65 + lane; bestpj = pc1; }
        }
        if (!(used & 4)) {
          double cur = -(double)s2 - ui0 - v2;
          if (cur < m2) { m2 = cur; way[129 + lane] = j0; }
          if (m2 < bestv) { bestv = m2; bestj = 129 + lane; bestpj = pc2; }
        }
#pragma unroll
        for (int off = 1; off < 64; off <<= 1) {
          double ov = __shfl_xor(bestv, off);
          int oj = __shfl_xor(bestj, off);
          int opj = __shfl_xor(bestpj, off);
          if (ov < bestv || (ov == bestv && oj < bestj)) {
            bestv = ov; bestj = oj; bestpj = opj;
          }
        }
        const double delta = bestv;

        if (rowmask & (1 << 1)) u1 += delta;
        if (rowmask & (1 << 2)) u2 += delta;
        if (rowmask & (1 << 3)) u3 += delta;
        if (rowmask & (1 << 4)) u4 += delta;
        if (rowmask & (1 << 5)) u5 += delta;
        if (rowmask & (1 << 6)) u6 += delta;
        if (rowmask & (1 << 7)) u7 += delta;
        if (rowmask & (1 << 8)) u8 += delta;
        if (used & 1) v0 -= delta; else m0 -= delta;
        if (used & 2) v1 -= delta; else m1 -= delta;
        if (used & 4) v2 -= delta; else m2 -= delta;

        j0 = bestj;
        pj0 = bestpj;
        if (pj0 == 0) break;
      }

      __syncthreads();  // way[] writes -> lane 0
      if (lane == 0) {
        int j = j0;
        while (j != 0) {
          int jp = way[j];
          p[j] = p[jp];
          j = jp;
        }
      }
      __syncthreads();  // p[] -> all lanes
      pc0 = p[1 + lane];
      pc1 = p[65 + lane];
      pc2 = p[129 + lane];
    }

    // collect matched sims for this round and mask them
    double s = 0.0;
    if (pc0) {
#pragma unroll
      for (int r = 0; r < 8; ++r)
        if (pc0 == r + 1) { s += (double)Sr[r][0]; Sr[r][0] = -100.f; }
    }
    if (pc1) {
#pragma unroll
      for (int r = 0; r < 8; ++r)
        if (pc1 == r + 1) { s += (double)Sr[r][1]; Sr[r][1] = -100.f; }
    }
    if (pc2) {
#pragma unroll
      for (int r = 0; r < 8; ++r)
        if (pc2 == r + 1) { s += (double)Sr[r][2]; Sr[r][2] = -100.f; }
    }
#pragma unroll
    for (int off = 1; off < 64; off <<= 1) s += __shfl_xor(s, off);
    total += s;
    __syncthreads();
  }

  if (lane == 0) out[b] = (float)(total * (1.0 / 32.0));
}

// ---------------------------------------------------------------------------
extern "C" void kernel_launch(void* const* d_in, const int* in_sizes, int n_in,
                              void* d_out, int out_size, void* d_ws,
                              size_t ws_size, hipStream_t stream) {
  const float* vf = (const float*)d_in[0];   // [256,193,768]
  const float* tf = (const float*)d_in[1];   // [256,768]
  const float* af = (const float*)d_in[2];   // [2048,768]
  const float* Wv = (const float*)d_in[4];
  const float* bv = (const float*)d_in[5];
  const float* Wtx = (const float*)d_in[6];
  const float* bt = (const float*)d_in[7];
  const float* Wp = (const float*)d_in[8];
  const float* bp = (const float*)d_in[9];
  const float* Wa = (const float*)d_in[10];
  const float* ba = (const float*)d_in[11];

  float* out = (float*)d_out;
  float* visual_out = out;               // 256*256 (textual at +65536)
  float* ls_out = out + 131072;          // 256

  char* ws = (char*)d_ws;
  unsigned short* patch = (unsigned short*)ws;                      // 24 MiB bf16
  unsigned short* Wt_s = (unsigned short*)(ws + (size_t)25165824);  // 384 KiB
  float* sim = (float*)(ws + (size_t)25165824 + 393216);            // 1.5 MiB

  // weight prep for patch MFMA
  prep_wt<<<768, 256, 0, stream>>>(Wp, Wt_s);

  // merged visual+textual fp32 projections (exact outputs)
  vt_gemm<<<dim3(4, 16), 256, 0, stream>>>(vf, tf, Wv, bv, Wtx, bt, visual_out);

  // big patch projection: bf16 MFMA + fused bias + L2-norm, bf16 out
  patch_gemm<<<256, 512, 0, stream>>>(vf, Wt_s, bp, patch);

  // fused att-projection + norm + sim (uniform control flow, std barriers)
  simatt<<<256, 512, 0, stream>>>(af, Wa, ba, patch, sim);

  // Hungarian + masked top-k rounds (round-4-proven kernel)
  hungarian_kernel<<<256, 64, 0, stream>>>(sim, ls_out);
}